// Round 1
// 99.634 us; speedup vs baseline: 1.0133x; 1.0133x over previous
//
#include <hip/hip_runtime.h>
#include <math.h>

typedef _Float16 f16x8  __attribute__((ext_vector_type(8)));    // MFMA A/B operand (4 VGPRs)
typedef _Float16 h2v    __attribute__((ext_vector_type(2)));
typedef float    f32x16 __attribute__((ext_vector_type(16)));   // MFMA C/D operand (32x32)
typedef float    f32x4  __attribute__((ext_vector_type(4)));
typedef __fp16   h2a    __attribute__((ext_vector_type(2)));    // cvt_pkrtz result
typedef unsigned u32x4  __attribute__((ext_vector_type(4)));

#define WS    10
#define HID   32
#define BDIM  256
#define NWAVE 4
#define GN    32                  // points per group = MFMA N
#define T_LEN 4096
#define NGRP  (T_LEN / GN)        // 128 groups per row
#define NIT   16                  // iters/wave: 2 group-indices x 2 rows = 4 chains/iter

__device__ inline unsigned pack2u(float a, float b) {
    h2a t = __builtin_amdgcn_cvt_pkrtz(a, b);   // a -> low16, b -> high16
    return __builtin_bit_cast(unsigned, t);
}
__device__ inline unsigned relu2(unsigned u) {  // v_pk_max_f16 with 0
    h2v x = __builtin_bit_cast(h2v, u);
    h2v z = {(_Float16)0.0f, (_Float16)0.0f};
    return __builtin_bit_cast(unsigned, __builtin_elementwise_max(x, z));
}

// ---- software-pipeline stage 1: issue the 12 global loads for iter I ----
// (loads land in statically-indexed register arrays; rule #20: no runtime
// buffer index anywhere, double-buffering is done with two NAMED buffers)
__device__ __forceinline__ void load_iter(int I, int wid, int n, int hi,
    const float* __restrict__ rA, const float* __restrict__ rB,
    float e2[4][2], float v6[4][6])
{
    const int g1  = wid + 8 * I;
    const int g2  = g1 + 4;
    const int t1  = g1 * GN + n;
    const int t2  = g2 * GN + n;
    const int w1  = (t1 >= WS) ? (t1 - WS) : 0;   // head points reuse window 0
    const int w2  = (t2 >= WS) ? (t2 - WS) : 0;

    // lane window bytes contiguous; 8B @ ws+8*hi = (e0,e1|e8,e9),
    // 24B @ ws+2 = e2..e7 (hi=1: in-bounds discard). 4B-aligned only.
    __builtin_memcpy(e2[0], rA + w1 + 8 * hi, 8);  __builtin_memcpy(v6[0], rA + w1 + 2, 24);
    __builtin_memcpy(e2[1], rB + w1 + 8 * hi, 8);  __builtin_memcpy(v6[1], rB + w1 + 2, 24);
    __builtin_memcpy(e2[2], rA + w2 + 8 * hi, 8);  __builtin_memcpy(v6[2], rA + w2 + 2, 24);
    __builtin_memcpy(e2[3], rB + w2 + 8 * hi, 8);  __builtin_memcpy(v6[3], rB + w2 + 2, 24);
}

// ---- software-pipeline stage 2: the stage-interleaved 4-chain MLP ----
__device__ __forceinline__ void compute_iter(int I, int wid, int n, int hi,
    const float e2[4][2], const float v6[4][6],
    f16x8 a1, f16x8 a2lo, f16x8 a2hi, f16x8 a3lo, f16x8 a3hi,
    f32x16 b1v, f32x16 b2v, float corr,
    float* __restrict__ oA, float* __restrict__ oB)
{
    f16x8 xb[4];
    #pragma unroll
    for (int c = 0; c < 4; ++c) {
        u32x4 xu;
        xu[0] = pack2u(e2[c][0], e2[c][1]);
        xu[1] = hi ? 0u : pack2u(v6[c][0], v6[c][1]);
        xu[2] = hi ? 0u : pack2u(v6[c][2], v6[c][3]);
        xu[3] = hi ? 0u : pack2u(v6[c][4], v6[c][5]);
        xb[c] = __builtin_bit_cast(f16x8, xu);
    }

    f32x16 d1[4];
    #pragma unroll
    for (int c = 0; c < 4; ++c)
        d1[c] = __builtin_amdgcn_mfma_f32_32x32x16_f16(a1, xb[c], b1v, 0, 0, 0);

    u32x4 p1lo[4], p1hi[4];
    #pragma unroll
    for (int c = 0; c < 4; ++c)
        #pragma unroll
        for (int q = 0; q < 4; ++q) {
            p1lo[c][q] = relu2(pack2u(d1[c][2 * q],     d1[c][2 * q + 1]));
            p1hi[c][q] = relu2(pack2u(d1[c][8 + 2 * q], d1[c][9 + 2 * q]));
        }

    f32x16 d2[4];
    #pragma unroll
    for (int c = 0; c < 4; ++c)
        d2[c] = __builtin_amdgcn_mfma_f32_32x32x16_f16(
                    a2lo, __builtin_bit_cast(f16x8, p1lo[c]), b2v, 0, 0, 0);
    #pragma unroll
    for (int c = 0; c < 4; ++c)
        d2[c] = __builtin_amdgcn_mfma_f32_32x32x16_f16(
                    a2hi, __builtin_bit_cast(f16x8, p1hi[c]), d2[c], 0, 0, 0);

    u32x4 p2lo[4], p2hi[4];
    #pragma unroll
    for (int c = 0; c < 4; ++c)
        #pragma unroll
        for (int q = 0; q < 4; ++q) {
            p2lo[c][q] = relu2(pack2u(d2[c][2 * q],     d2[c][2 * q + 1]));
            p2hi[c][q] = relu2(pack2u(d2[c][8 + 2 * q], d2[c][9 + 2 * q]));
        }

    f32x16 d3[4];
    #pragma unroll
    for (int c = 0; c < 4; ++c)
        d3[c] = __builtin_amdgcn_mfma_f32_32x32x16_f16(
                    a3lo, __builtin_bit_cast(f16x8, p2lo[c]), b2v, 0, 0, 0);
    #pragma unroll
    for (int c = 0; c < 4; ++c)
        d3[c] = __builtin_amdgcn_mfma_f32_32x32x16_f16(
                    a3hi, __builtin_bit_cast(f16x8, p2hi[c]), d3[c], 0, 0, 0);

    float o[4];
    #pragma unroll
    for (int c = 0; c < 4; ++c)
        o[c] = 0.5f * __builtin_amdgcn_rcpf(1.0f + __expf(-(d3[c][0] + corr)));

    const int g1 = wid + 8 * I;
    const int g2 = g1 + 4;
    const int t1 = g1 * GN + n;
    const int t2 = g2 * GN + n;
    if (hi == 0) {
        oA[t1] = o[0];
        oB[t1] = o[1];
        oA[t2] = o[2];
        oB[t2] = o[3];
    }
}

// grid 512 x 2 rows/block at (256,2): exactly 2 blocks/CU, ALL co-resident,
// single round, zero tail. ILP=4 chains/iter; 1-deep software pipeline:
// loads for iter i+1 issued before compute of iter i (the ~450-cycle MLP
// chain hides the L1/L2 load latency that was previously exposed at the
// top of every iteration at only 2 waves/SIMD).
__global__ __launch_bounds__(BDIM, 2)
void hurst_pipe(const float* __restrict__ returns,
                const float* __restrict__ W1, const float* __restrict__ b1,
                const float* __restrict__ W2, const float* __restrict__ b2,
                const float* __restrict__ W3, const float* __restrict__ b3,
                float* __restrict__ out)
{
    const int tid  = threadIdx.x;
    const int wid  = tid >> 6;
    const int lane = tid & 63;
    const int n    = lane & 31;    // MFMA m (A-row) / n (B/C col)
    const int hi   = lane >> 5;    // k-half (A/B) / row-half (C/D)

    // ---- bias C-operands in C-layout: row(r)=(r&3)+8(r>>2)+4hi ----
    f32x16 b1v, b2v;
    #pragma unroll
    for (int i = 0; i < 4; ++i) {
        const f32x4 v1 = ((const f32x4*)b1)[2 * i + hi];
        const f32x4 v2 = ((const f32x4*)b2)[2 * i + hi];
        #pragma unroll
        for (int o = 0; o < 4; ++o) {
            b1v[4 * i + o] = v1[o];
            b2v[4 * i + o] = v2[o];
        }
    }
    const float corr = b3[0] - b2[4 * hi];   // undoes b2v[0] riding L3's C-init

    // ---- A-frags; phi(k)=swap(bit2,bit3) absorbs the C->B layout permutation
    // between stages (verified r6-r12, absmax 1.95e-3) ----
    f16x8 a1, a2lo, a2hi, a3lo, a3hi;
    #pragma unroll
    for (int jj = 0; jj < 8; ++jj) {
        const int k  = 8 * hi + jj;
        a1[jj] = (k < WS) ? (_Float16)W1[k * HID + n] : (_Float16)0.0f;   // W1^T, K 10->16 pad
        const int kf = (k & 3) | ((k & 4) << 1) | ((k & 8) >> 1);         // phi: swap bits 2<->3
        a2lo[jj] = (_Float16)W2[kf * HID + n];
        a2hi[jj] = (_Float16)W2[(16 + kf) * HID + n];
        a3lo[jj] = (_Float16)W3[kf];          // broadcast over m
        a3hi[jj] = (_Float16)W3[16 + kf];
    }

    const float* rA = returns + (size_t)(2 * blockIdx.x) * T_LEN;
    const float* rB = rA + T_LEN;
    float*       oA = out + (size_t)(2 * blockIdx.x) * T_LEN;
    float*       oB = oA + T_LEN;

    // two named buffers; all indices compile-time constant after inlining
    float e2A[4][2], v6A[4][6], e2B[4][2], v6B[4][6];

    load_iter(0, wid, n, hi, rA, rB, e2A, v6A);
    for (int ii = 0; ii < NIT / 2; ++ii) {
        load_iter(2 * ii + 1, wid, n, hi, rA, rB, e2B, v6B);
        compute_iter(2 * ii, wid, n, hi, e2A, v6A,
                     a1, a2lo, a2hi, a3lo, a3hi, b1v, b2v, corr, oA, oB);
        if (ii + 1 < NIT / 2)
            load_iter(2 * ii + 2, wid, n, hi, rA, rB, e2A, v6A);
        compute_iter(2 * ii + 1, wid, n, hi, e2B, v6B,
                     a1, a2lo, a2hi, a3lo, a3hi, b1v, b2v, corr, oA, oB);
    }
}

extern "C" void kernel_launch(void* const* d_in, const int* in_sizes, int n_in,
                              void* d_out, int out_size, void* d_ws, size_t ws_size,
                              hipStream_t stream) {
    const float* returns = (const float*)d_in[0];
    const float* W1      = (const float*)d_in[1];
    const float* b1      = (const float*)d_in[2];
    const float* W2      = (const float*)d_in[3];
    const float* b2      = (const float*)d_in[4];
    const float* W3      = (const float*)d_in[5];
    const float* b3      = (const float*)d_in[6];
    float* out = (float*)d_out;

    const int B = out_size / T_LEN;   // 1024

    dim3 grid(B / 2, 1, 1);           // 512 blocks x 2 rows: all co-resident, one round
    dim3 block(BDIM, 1, 1);
    hurst_pipe<<<grid, block, 0, stream>>>(returns, W1, b1, W2, b2, W3, b3, out);
}